// Round 1
// baseline (298.348 us; speedup 1.0000x reference)
//
#include <hip/hip_runtime.h>

#define TT 512
#define BB 1024
#define FF 16
#define HH 32
#define OO 8

__device__ __forceinline__ float rcp_fast(float x) { return __builtin_amdgcn_rcpf(x); }
__device__ __forceinline__ float sigm(float x) { return rcp_fast(1.0f + __expf(-x)); }
__device__ __forceinline__ float tanh_fast(float x) { return 1.0f - 2.0f * rcp_fast(1.0f + __expf(2.0f * x)); }

// One wave (64 threads) per block; each block runs TWO independent sequences
// (adjacent batch rows) of one direction. Lane (bl, kk): bl = seq-in-pair,
// kk = hidden index. Each lane owns gate rows {kk, kk+32, kk+64, kk+96}
// (i,f,g,o), so the c/h update is lane-local. h is broadcast through a tiny
// double-buffered LDS array (8x ds_read_b128, 2-address broadcast => no bank
// conflicts). x is prefetched one step ahead into registers.
__global__ __launch_bounds__(64, 1)
void lstm_seq_kernel(const float* __restrict__ x,
                     const float* __restrict__ Wih_f, const float* __restrict__ Whh_f,
                     const float* __restrict__ b_f,
                     const float* __restrict__ Wih_b, const float* __restrict__ Whh_b,
                     const float* __restrict__ b_b,
                     float* __restrict__ hidden)
{
    const int bid  = blockIdx.x;          // 0..1023
    const int dir  = bid >> 9;            // 0 = fwd, 1 = bwd
    const int b0   = (bid & 511) * 2;     // first batch row of the pair
    const int lane = threadIdx.x;         // 0..63
    const int bl   = lane >> 5;           // 0/1: which sequence of the pair
    const int kk   = lane & 31;           // hidden index
    const int bb   = b0 + bl;             // this lane's batch row

    const float* __restrict__ Wih  = dir ? Wih_b : Wih_f;
    const float* __restrict__ Whh  = dir ? Whh_b : Whh_f;
    const float* __restrict__ bias = dir ? b_b   : b_f;

    // --- stage weights into VGPRs: 4 gate rows x (16 + 32) = 192 regs/lane ---
    float wih[4][FF];
    float whh[4][HH];
#pragma unroll
    for (int g = 0; g < 4; ++g) {
        const int row = kk + g * HH;
        const float4* pi = (const float4*)(Wih + row * FF);
#pragma unroll
        for (int q = 0; q < FF / 4; ++q) {
            float4 v = pi[q];
            wih[g][q*4+0] = v.x; wih[g][q*4+1] = v.y;
            wih[g][q*4+2] = v.z; wih[g][q*4+3] = v.w;
        }
        const float4* ph = (const float4*)(Whh + row * HH);
#pragma unroll
        for (int q = 0; q < HH / 4; ++q) {
            float4 v = ph[q];
            whh[g][q*4+0] = v.x; whh[g][q*4+1] = v.y;
            whh[g][q*4+2] = v.z; whh[g][q*4+3] = v.w;
        }
    }
    const float bi = bias[kk];
    const float bf = bias[kk + HH];
    const float bg = bias[kk + 2 * HH];
    const float bo = bias[kk + 3 * HH];

    __shared__ float hbuf[2][64];   // [buffer][bl*32 + kk]
    hbuf[0][lane] = 0.0f;
    __syncthreads();

    float c = 0.0f, h = 0.0f;

    const size_t xstride = (size_t)BB * FF;

    // preload x for step 0
    float xr[FF];
    {
        const int ts0 = dir ? (TT - 1) : 0;
        const float4* xp = (const float4*)(x + (size_t)ts0 * xstride + (size_t)bb * FF);
        float4 v0 = xp[0], v1 = xp[1], v2 = xp[2], v3 = xp[3];
        xr[0]=v0.x;  xr[1]=v0.y;  xr[2]=v0.z;  xr[3]=v0.w;
        xr[4]=v1.x;  xr[5]=v1.y;  xr[6]=v1.z;  xr[7]=v1.w;
        xr[8]=v2.x;  xr[9]=v2.y;  xr[10]=v2.z; xr[11]=v2.w;
        xr[12]=v3.x; xr[13]=v3.y; xr[14]=v3.z; xr[15]=v3.w;
    }

#pragma unroll 2
    for (int t = 0; t < TT; ++t) {
        const int p = t & 1;

        // issue h-broadcast reads early (latency hides under input FMAs)
        const float4* hv = (const float4*)&hbuf[p][bl * HH];
        float4 h0 = hv[0], h1 = hv[1], h2 = hv[2], h3 = hv[3];
        float4 h4 = hv[4], h5 = hv[5], h6 = hv[6], h7 = hv[7];

        // prefetch x for t+1 (clamped at the end; value unused then)
        const int tn   = (t + 1 < TT) ? (t + 1) : t;
        const int tsrc = dir ? (TT - 1 - tn) : tn;
        const float4* xnp = (const float4*)(x + (size_t)tsrc * xstride + (size_t)bb * FF);
        float4 n0 = xnp[0], n1 = xnp[1], n2 = xnp[2], n3 = xnp[3];

        // input projection (independent of h)
        float ai = bi, af = bf, ag = bg, ao = bo;
#pragma unroll
        for (int f = 0; f < FF; ++f) {
            const float xv = xr[f];
            ai += xv * wih[0][f];
            af += xv * wih[1][f];
            ag += xv * wih[2][f];
            ao += xv * wih[3][f];
        }

        // recurrent part
        float hr[HH];
        hr[0]=h0.x;  hr[1]=h0.y;  hr[2]=h0.z;  hr[3]=h0.w;
        hr[4]=h1.x;  hr[5]=h1.y;  hr[6]=h1.z;  hr[7]=h1.w;
        hr[8]=h2.x;  hr[9]=h2.y;  hr[10]=h2.z; hr[11]=h2.w;
        hr[12]=h3.x; hr[13]=h3.y; hr[14]=h3.z; hr[15]=h3.w;
        hr[16]=h4.x; hr[17]=h4.y; hr[18]=h4.z; hr[19]=h4.w;
        hr[20]=h5.x; hr[21]=h5.y; hr[22]=h5.z; hr[23]=h5.w;
        hr[24]=h6.x; hr[25]=h6.y; hr[26]=h6.z; hr[27]=h6.w;
        hr[28]=h7.x; hr[29]=h7.y; hr[30]=h7.z; hr[31]=h7.w;
#pragma unroll
        for (int k = 0; k < HH; ++k) {
            const float hk = hr[k];
            ai += hk * whh[0][k];
            af += hk * whh[1][k];
            ag += hk * whh[2][k];
            ao += hk * whh[3][k];
        }

        // gates + state update (lane-local)
        const float si = sigm(ai);
        const float sf = sigm(af);
        const float so = sigm(ao);
        const float tg = tanh_fast(ag);
        c = sf * c + si * tg;
        h = so * tanh_fast(c);

        hbuf[p ^ 1][bl * HH + kk] = h;
        __syncthreads();

        xr[0]=n0.x;  xr[1]=n0.y;  xr[2]=n0.z;  xr[3]=n0.w;
        xr[4]=n1.x;  xr[5]=n1.y;  xr[6]=n1.z;  xr[7]=n1.w;
        xr[8]=n2.x;  xr[9]=n2.y;  xr[10]=n2.z; xr[11]=n2.w;
        xr[12]=n3.x; xr[13]=n3.y; xr[14]=n3.z; xr[15]=n3.w;
    }

    // hidden[b][0:32] = h_fwd, hidden[b][32:64] = h_bwd
    hidden[(size_t)bb * 64 + dir * HH + kk] = h;
}

// FC1 + per-block partial of FC2. Grid: 32 blocks x 256 threads.
// Block covers 32 batch rows; thread (r,o) computes hidden_fc[row][o], which
// is exactly flat[blockIdx*256 + tid]; then each thread contributes
// W_fc_o[o2][flat_idx] * flat_val for all 8 outputs, block-reduced.
__global__ __launch_bounds__(256)
void fc_partial_kernel(const float* __restrict__ hidden,
                       const float* __restrict__ Wfh, const float* __restrict__ bfh,
                       const float* __restrict__ Wfo,
                       float* __restrict__ partials)
{
    __shared__ float wsh[OO * 64];
    const int tid = threadIdx.x;
    for (int i = tid; i < OO * 64; i += 256) wsh[i] = Wfh[i];
    __syncthreads();

    const int r   = tid >> 3;                 // 0..31 local row
    const int o   = tid & 7;                  // 0..7 class
    const int row = blockIdx.x * 32 + r;

    const float* hrow = hidden + (size_t)row * 64;
    float acc = bfh[o];
#pragma unroll
    for (int j = 0; j < 64; ++j) acc += hrow[j] * wsh[o * 64 + j];

    const int fidx = blockIdx.x * 256 + tid;  // flat index (= row*8 + o)

    float pv[OO];
#pragma unroll
    for (int o2 = 0; o2 < OO; ++o2) pv[o2] = Wfo[(size_t)o2 * (BB * OO) + fidx] * acc;

    __shared__ float red[4][OO];
#pragma unroll
    for (int o2 = 0; o2 < OO; ++o2) {
        float v = pv[o2];
        for (int off = 32; off > 0; off >>= 1) v += __shfl_down(v, off);
        if ((tid & 63) == 0) red[tid >> 6][o2] = v;
    }
    __syncthreads();
    if (tid < OO) {
        partials[blockIdx.x * OO + tid] =
            red[0][tid] + red[1][tid] + red[2][tid] + red[3][tid];
    }
}

__global__ void finalize_kernel(const float* __restrict__ partials,
                                const float* __restrict__ bfo,
                                float* __restrict__ out)
{
    __shared__ float s[OO];
    const int tid = threadIdx.x;
    if (tid < OO) {
        float acc = bfo[tid];
        for (int b = 0; b < 32; ++b) acc += partials[b * OO + tid];
        s[tid] = acc;
    }
    __syncthreads();
    if (tid == 0) {
        float m = s[0];
        for (int i = 1; i < OO; ++i) m = fmaxf(m, s[i]);
        float e[OO], sum = 0.0f;
        for (int i = 0; i < OO; ++i) { e[i] = expf(s[i] - m); sum += e[i]; }
        for (int i = 0; i < OO; ++i) out[i] = e[i] / sum;
    }
}

extern "C" void kernel_launch(void* const* d_in, const int* in_sizes, int n_in,
                              void* d_out, int out_size, void* d_ws, size_t ws_size,
                              hipStream_t stream) {
    const float* x     = (const float*)d_in[0];
    const float* Wih_f = (const float*)d_in[1];
    const float* Whh_f = (const float*)d_in[2];
    const float* b_f   = (const float*)d_in[3];
    const float* Wih_b = (const float*)d_in[4];
    const float* Whh_b = (const float*)d_in[5];
    const float* b_b   = (const float*)d_in[6];
    const float* Wfh   = (const float*)d_in[7];
    const float* bfh   = (const float*)d_in[8];
    const float* Wfo   = (const float*)d_in[9];
    const float* bfo   = (const float*)d_in[10];

    float* hidden   = (float*)d_ws;              // 1024*64 floats = 256 KB
    float* partials = hidden + (size_t)BB * 64;  // 32*8 floats

    lstm_seq_kernel<<<BB, 64, 0, stream>>>(x, Wih_f, Whh_f, b_f,
                                           Wih_b, Whh_b, b_b, hidden);
    fc_partial_kernel<<<32, 256, 0, stream>>>(hidden, Wfh, bfh, Wfo, partials);
    finalize_kernel<<<1, 64, 0, stream>>>(partials, bfo, (float*)d_out);
}

// Round 2
// 284.708 us; speedup vs baseline: 1.0479x; 1.0479x over previous
//
#include <hip/hip_runtime.h>

#define TT 512
#define BB 1024
#define FF 16
#define HH 32
#define OO 8

typedef float v2f __attribute__((ext_vector_type(2)));

__device__ __forceinline__ float rcp_fast(float x) { return __builtin_amdgcn_rcpf(x); }
__device__ __forceinline__ float sigm(float x) { return rcp_fast(1.0f + __expf(-x)); }

// One wave (64 lanes) per block, ONE sequence per wave => 2048 blocks,
// 8 waves/CU (2 per SIMD) so two waves interleave to hide LDS/trans latency.
// Lane (hi,kk): hi=0 owns gate rows {kk (i), kk+64 (g)}; hi=1 owns
// {kk+32 (f), kk+96 (o)} -> only 96 weight floats/lane (no spill).
// i/f/g/o recombine via one shfl_xor(32) pair. Dot products use packed
// v_pk_fma_f32 (2 fp32/instr). h broadcast via 32-float LDS buffer
// (same-address reads = free broadcast).
__global__ __launch_bounds__(64, 2)
void lstm_seq_kernel(const float* __restrict__ x,
                     const float* __restrict__ Wih_f, const float* __restrict__ Whh_f,
                     const float* __restrict__ b_f,
                     const float* __restrict__ Wih_b, const float* __restrict__ Whh_b,
                     const float* __restrict__ b_b,
                     float* __restrict__ hidden)
{
    const int bid  = blockIdx.x;          // 0..2047
    const int dir  = bid >> 10;           // 0 = fwd, 1 = bwd
    const int bb   = bid & (BB - 1);      // batch row
    const int lane = threadIdx.x;
    const int hi   = lane >> 5;           // 0: i,g rows   1: f,o rows
    const int kk   = lane & 31;

    const float* __restrict__ Wih  = dir ? Wih_b : Wih_f;
    const float* __restrict__ Whh  = dir ? Whh_b : Whh_f;
    const float* __restrict__ bias = dir ? b_b   : b_f;

    const int row0 = kk + hi * HH;        // i or f row
    const int row1 = row0 + 2 * HH;       // g or o row

    // ---- stage this lane's 2 weight rows into VGPRs as packed pairs ----
    v2f w0i[FF / 2], w1i[FF / 2], w0h[HH / 2], w1h[HH / 2];
#pragma unroll
    for (int q = 0; q < FF / 4; ++q) {
        float4 v = ((const float4*)(Wih + row0 * FF))[q];
        w0i[2*q]   = (v2f){v.x, v.y};
        w0i[2*q+1] = (v2f){v.z, v.w};
        float4 u = ((const float4*)(Wih + row1 * FF))[q];
        w1i[2*q]   = (v2f){u.x, u.y};
        w1i[2*q+1] = (v2f){u.z, u.w};
    }
#pragma unroll
    for (int q = 0; q < HH / 4; ++q) {
        float4 v = ((const float4*)(Whh + row0 * HH))[q];
        w0h[2*q]   = (v2f){v.x, v.y};
        w0h[2*q+1] = (v2f){v.z, v.w};
        float4 u = ((const float4*)(Whh + row1 * HH))[q];
        w1h[2*q]   = (v2f){u.x, u.y};
        w1h[2*q+1] = (v2f){u.z, u.w};
    }
    const float b0 = bias[row0];
    const float b1 = bias[row1];

    // loop-invariant gate-nonlinearity selectors:
    //   hi=0: v1 = tanh(a1)  = 2*sigm(2*a1) - 1   (am=2, pm=2, pa=-1)
    //   hi=1: v1 = sigm(a1)                        (am=1, pm=1, pa=0)
    const float am = hi ? 1.0f : 2.0f;
    const float pm = am;
    const float pa = hi ? 0.0f : -1.0f;

    __shared__ __align__(16) float hbuf[2 * HH];  // both halves write copies
    hbuf[lane] = 0.0f;
    __syncthreads();

    float c = 0.0f, h = 0.0f;

    // x pointer walk (wave-uniform address -> scalar loads)
    const float* xp = x + (size_t)(dir ? (TT - 1) : 0) * (BB * FF) + (size_t)bb * FF;
    const ptrdiff_t xstep = dir ? -(ptrdiff_t)(BB * FF) : (ptrdiff_t)(BB * FF);

    v2f xr[FF / 2];
    {
        float4 v0 = ((const float4*)xp)[0], v1 = ((const float4*)xp)[1];
        float4 v2 = ((const float4*)xp)[2], v3 = ((const float4*)xp)[3];
        xr[0] = (v2f){v0.x, v0.y}; xr[1] = (v2f){v0.z, v0.w};
        xr[2] = (v2f){v1.x, v1.y}; xr[3] = (v2f){v1.z, v1.w};
        xr[4] = (v2f){v2.x, v2.y}; xr[5] = (v2f){v2.z, v2.w};
        xr[6] = (v2f){v3.x, v3.y}; xr[7] = (v2f){v3.z, v3.w};
    }
    xp += xstep;

#pragma unroll 2
    for (int t = 0; t < TT; ++t) {
        // h broadcast: all 64 lanes read the same 32 floats (free broadcast)
        const float4* hv = (const float4*)hbuf;
        float4 h0 = hv[0], h1 = hv[1], h2 = hv[2], h3 = hv[3];
        float4 h4 = hv[4], h5 = hv[5], h6 = hv[6], h7 = hv[7];

        // prefetch x for t+1 (clamped on last iter; value unused then)
        const float* xpl = (t + 1 < TT) ? xp : (xp - xstep);
        float4 n0 = ((const float4*)xpl)[0], n1 = ((const float4*)xpl)[1];
        float4 n2 = ((const float4*)xpl)[2], n3 = ((const float4*)xpl)[3];

        // packed dot products: 48 v_pk_fma_f32
        v2f acc0 = (v2f){0.0f, 0.0f}, acc1 = (v2f){0.0f, 0.0f};
#pragma unroll
        for (int q = 0; q < FF / 2; ++q) {
            acc0 = __builtin_elementwise_fma(xr[q], w0i[q], acc0);
            acc1 = __builtin_elementwise_fma(xr[q], w1i[q], acc1);
        }
        v2f hr[HH / 2];
        hr[0] = (v2f){h0.x, h0.y};  hr[1] = (v2f){h0.z, h0.w};
        hr[2] = (v2f){h1.x, h1.y};  hr[3] = (v2f){h1.z, h1.w};
        hr[4] = (v2f){h2.x, h2.y};  hr[5] = (v2f){h2.z, h2.w};
        hr[6] = (v2f){h3.x, h3.y};  hr[7] = (v2f){h3.z, h3.w};
        hr[8] = (v2f){h4.x, h4.y};  hr[9] = (v2f){h4.z, h4.w};
        hr[10] = (v2f){h5.x, h5.y}; hr[11] = (v2f){h5.z, h5.w};
        hr[12] = (v2f){h6.x, h6.y}; hr[13] = (v2f){h6.z, h6.w};
        hr[14] = (v2f){h7.x, h7.y}; hr[15] = (v2f){h7.z, h7.w};
#pragma unroll
        for (int q = 0; q < HH / 2; ++q) {
            acc0 = __builtin_elementwise_fma(hr[q], w0h[q], acc0);
            acc1 = __builtin_elementwise_fma(hr[q], w1h[q], acc1);
        }
        const float a0 = b0 + acc0.x + acc0.y;   // i (hi=0) or f (hi=1)
        const float a1 = b1 + acc1.x + acc1.y;   // g (hi=0) or o (hi=1)

        const float v0 = sigm(a0);
        const float s  = sigm(a1 * am);
        const float v1 = fmaf(s, pm, pa);

        const float p0 = __shfl_xor(v0, 32);
        const float p1 = __shfl_xor(v1, 32);

        const float fs = hi ? v0 : p0;
        const float is = hi ? p0 : v0;
        const float gt = hi ? p1 : v1;
        const float os = hi ? v1 : p1;

        c = fmaf(fs, c, is * gt);                 // identical in both halves
        const float th = fmaf(2.0f, sigm(2.0f * c), -1.0f);  // tanh(c)
        h = os * th;

        __syncthreads();            // single wave: reads above are done
        hbuf[lane] = h;             // both halves write identical copies
        __syncthreads();

        xr[0] = (v2f){n0.x, n0.y}; xr[1] = (v2f){n0.z, n0.w};
        xr[2] = (v2f){n1.x, n1.y}; xr[3] = (v2f){n1.z, n1.w};
        xr[4] = (v2f){n2.x, n2.y}; xr[5] = (v2f){n2.z, n2.w};
        xr[6] = (v2f){n3.x, n3.y}; xr[7] = (v2f){n3.z, n3.w};
        xp += xstep;
    }

    // hidden[b][0:32] = h_fwd, hidden[b][32:64] = h_bwd
    if (hi == 0) hidden[(size_t)bb * 64 + dir * HH + kk] = h;
}

// FC1 + per-block partial of FC2. Grid: 32 blocks x 256 threads.
__global__ __launch_bounds__(256)
void fc_partial_kernel(const float* __restrict__ hidden,
                       const float* __restrict__ Wfh, const float* __restrict__ bfh,
                       const float* __restrict__ Wfo,
                       float* __restrict__ partials)
{
    __shared__ float wsh[OO * 64];
    const int tid = threadIdx.x;
    for (int i = tid; i < OO * 64; i += 256) wsh[i] = Wfh[i];
    __syncthreads();

    const int r   = tid >> 3;                 // 0..31 local row
    const int o   = tid & 7;                  // 0..7 class
    const int row = blockIdx.x * 32 + r;

    const float* hrow = hidden + (size_t)row * 64;
    float acc = bfh[o];
#pragma unroll
    for (int j = 0; j < 64; ++j) acc += hrow[j] * wsh[o * 64 + j];

    const int fidx = blockIdx.x * 256 + tid;  // flat index (= row*8 + o)

    float pv[OO];
#pragma unroll
    for (int o2 = 0; o2 < OO; ++o2) pv[o2] = Wfo[(size_t)o2 * (BB * OO) + fidx] * acc;

    __shared__ float red[4][OO];
#pragma unroll
    for (int o2 = 0; o2 < OO; ++o2) {
        float v = pv[o2];
        for (int off = 32; off > 0; off >>= 1) v += __shfl_down(v, off);
        if ((tid & 63) == 0) red[tid >> 6][o2] = v;
    }
    __syncthreads();
    if (tid < OO) {
        partials[blockIdx.x * OO + tid] =
            red[0][tid] + red[1][tid] + red[2][tid] + red[3][tid];
    }
}

__global__ void finalize_kernel(const float* __restrict__ partials,
                                const float* __restrict__ bfo,
                                float* __restrict__ out)
{
    __shared__ float s[OO];
    const int tid = threadIdx.x;
    if (tid < OO) {
        float acc = bfo[tid];
        for (int b = 0; b < 32; ++b) acc += partials[b * OO + tid];
        s[tid] = acc;
    }
    __syncthreads();
    if (tid == 0) {
        float m = s[0];
        for (int i = 1; i < OO; ++i) m = fmaxf(m, s[i]);
        float e[OO], sum = 0.0f;
        for (int i = 0; i < OO; ++i) { e[i] = expf(s[i] - m); sum += e[i]; }
        for (int i = 0; i < OO; ++i) out[i] = e[i] / sum;
    }
}

extern "C" void kernel_launch(void* const* d_in, const int* in_sizes, int n_in,
                              void* d_out, int out_size, void* d_ws, size_t ws_size,
                              hipStream_t stream) {
    const float* x     = (const float*)d_in[0];
    const float* Wih_f = (const float*)d_in[1];
    const float* Whh_f = (const float*)d_in[2];
    const float* b_f   = (const float*)d_in[3];
    const float* Wih_b = (const float*)d_in[4];
    const float* Whh_b = (const float*)d_in[5];
    const float* b_b   = (const float*)d_in[6];
    const float* Wfh   = (const float*)d_in[7];
    const float* bfh   = (const float*)d_in[8];
    const float* Wfo   = (const float*)d_in[9];
    const float* bfo   = (const float*)d_in[10];

    float* hidden   = (float*)d_ws;              // 1024*64 floats = 256 KB
    float* partials = hidden + (size_t)BB * 64;  // 32*8 floats

    lstm_seq_kernel<<<2 * BB, 64, 0, stream>>>(x, Wih_f, Whh_f, b_f,
                                               Wih_b, Whh_b, b_b, hidden);
    fc_partial_kernel<<<32, 256, 0, stream>>>(hidden, Wfh, bfh, Wfo, partials);
    finalize_kernel<<<1, 64, 0, stream>>>(partials, bfo, (float*)d_out);
}

// Round 3
// 228.892 us; speedup vs baseline: 1.3034x; 1.2439x over previous
//
#include <hip/hip_runtime.h>

#define TT 512
#define BB 1024
#define FF 16
#define HH 32
#define OO 8
#define CH 16   // timesteps per x-chunk staged through LDS

typedef float v2f __attribute__((ext_vector_type(2)));

__device__ __forceinline__ float rcp_fast(float x) { return __builtin_amdgcn_rcpf(x); }
__device__ __forceinline__ float sigm(float x) { return rcp_fast(1.0f + __expf(-x)); }
__device__ __forceinline__ float tanh_fast(float x) { return fmaf(2.0f, sigm(2.0f * x), -1.0f); }

#define PIN6(a,b,c,d,e,f) asm volatile("" :: "v"(a),"v"(b),"v"(c),"v"(d),"v"(e),"v"(f))
#define PIN4(a,b,c,d)     asm volatile("" :: "v"(a),"v"(b),"v"(c),"v"(d))

// One wave per block, one sequence per wave (2048 blocks, 2 waves/SIMD).
// k-split layout: lane (hi,kk) computes ALL 4 gate rows {kk,+32,+64,+96}
// over k-half hi: x[k] for k in [hi*8,hi*8+8), h[k] for k in [hi*16,hi*16+16).
// 96 weight floats/lane as 48 v2f, PINNED into VGPRs via empty asm so the
// compiler cannot re-load them per step. Gate recombine: 4x shfl_xor(32).
// x is staged through LDS in 16-step chunks: one dwordx4 per lane covers a
// whole chunk, issued 16 steps ahead (HBM latency off the critical chain).
// h double-buffered in LDS -> single barrier per step.
__global__ __launch_bounds__(64, 2)
void lstm_seq_kernel(const float* __restrict__ x,
                     const float* __restrict__ Wih_f, const float* __restrict__ Whh_f,
                     const float* __restrict__ b_f,
                     const float* __restrict__ Wih_b, const float* __restrict__ Whh_b,
                     const float* __restrict__ b_b,
                     float* __restrict__ hidden)
{
    const int bid  = blockIdx.x;          // 0..2047
    const int dir  = bid >> 10;           // 0 = fwd, 1 = bwd
    const int bb   = bid & (BB - 1);      // batch row
    const int lane = threadIdx.x;
    const int hi   = lane >> 5;           // k-half
    const int kk   = lane & 31;           // hidden index (row)

    const float* __restrict__ Wih  = dir ? Wih_b : Wih_f;
    const float* __restrict__ Whh  = dir ? Whh_b : Whh_f;
    const float* __restrict__ bias = dir ? b_b   : b_f;

    // ---- stage this lane's weight slices: 4 gates x (8 x-k + 16 h-k) ----
    v2f wi[4][4];   // x-part:  4 v2f per gate
    v2f wh[4][8];   // h-part:  8 v2f per gate
    v2f pb2[4];     // bias (hi==0 only) packed as {b,0}
#pragma unroll
    for (int g = 0; g < 4; ++g) {
        const int row = kk + g * HH;
        const float4* pi = (const float4*)(Wih + row * FF + hi * 8);
        float4 a = pi[0], b = pi[1];
        wi[g][0] = (v2f){a.x, a.y}; wi[g][1] = (v2f){a.z, a.w};
        wi[g][2] = (v2f){b.x, b.y}; wi[g][3] = (v2f){b.z, b.w};
        const float4* ph = (const float4*)(Whh + row * HH + hi * 16);
        float4 c0 = ph[0], c1 = ph[1], c2 = ph[2], c3 = ph[3];
        wh[g][0] = (v2f){c0.x, c0.y}; wh[g][1] = (v2f){c0.z, c0.w};
        wh[g][2] = (v2f){c1.x, c1.y}; wh[g][3] = (v2f){c1.z, c1.w};
        wh[g][4] = (v2f){c2.x, c2.y}; wh[g][5] = (v2f){c2.z, c2.w};
        wh[g][6] = (v2f){c3.x, c3.y}; wh[g][7] = (v2f){c3.z, c3.w};
        pb2[g] = (v2f){hi ? 0.0f : bias[row], 0.0f};
    }
    // pin weights in VGPRs: pre-loop asm use blocks load-sinking into the loop
    PIN6(wi[0][0], wi[0][1], wi[0][2], wi[0][3], wi[1][0], wi[1][1]);
    PIN6(wi[1][2], wi[1][3], wi[2][0], wi[2][1], wi[2][2], wi[2][3]);
    PIN6(wi[3][0], wi[3][1], wi[3][2], wi[3][3], wh[0][0], wh[0][1]);
    PIN6(wh[0][2], wh[0][3], wh[0][4], wh[0][5], wh[0][6], wh[0][7]);
    PIN6(wh[1][0], wh[1][1], wh[1][2], wh[1][3], wh[1][4], wh[1][5]);
    PIN6(wh[1][6], wh[1][7], wh[2][0], wh[2][1], wh[2][2], wh[2][3]);
    PIN6(wh[2][4], wh[2][5], wh[2][6], wh[2][7], wh[3][0], wh[3][1]);
    PIN6(wh[3][2], wh[3][3], wh[3][4], wh[3][5], wh[3][6], wh[3][7]);
    PIN4(pb2[0], pb2[1], pb2[2], pb2[3]);

    __shared__ __align__(16) float xsb[2 * CH * FF];  // 2 KB: two x chunks
    __shared__ __align__(16) float hsb[2 * HH];       // double-buffered h

    // ---- x chunk-staging pointers: lane (sl,wl) covers step sl, quarter wl ----
    const int sl = lane >> 2;             // 0..15: step within chunk
    const int wl = lane & 3;              // 0..3 : float4 quarter
    const int t0 = dir ? (TT - 1 - sl) : sl;
    const float* xp = x + (size_t)t0 * (BB * FF) + (size_t)bb * FF + wl * 4;
    const ptrdiff_t dstep = (dir ? -(ptrdiff_t)CH : (ptrdiff_t)CH) * (BB * FF);

    // prologue: stage chunk 0, zero h buffer 0
    {
        float4 f0 = *(const float4*)xp;
        *(float4*)(xsb + sl * FF + wl * 4) = f0;
    }
    xp += dstep;
    if (hi == 0) hsb[kk] = 0.0f;
    __syncthreads();

    float c = 0.0f, h = 0.0f;

    for (int ci = 0; ci < TT / CH; ++ci) {
        const bool more = (ci + 1 < TT / CH);
        float4 nf;
        if (more) { nf = *(const float4*)xp; xp += dstep; }   // chunk ci+1, 16 steps early

        const int xbase = (ci & 1) * (CH * FF) + hi * 8;
#pragma unroll
        for (int tt = 0; tt < CH; ++tt) {
            // x slice (broadcast within half-wave, conflict-free)
            const float* xr = xsb + xbase + tt * FF;
            float4 xa = *(const float4*)(xr);
            float4 xc = *(const float4*)(xr + 4);
            // h slice
            const float* hr = hsb + (tt & 1) * HH + hi * 16;
            float4 h0 = *(const float4*)(hr);
            float4 h1 = *(const float4*)(hr + 4);
            float4 h2 = *(const float4*)(hr + 8);
            float4 h3 = *(const float4*)(hr + 12);

            v2f a0 = pb2[0], a1 = pb2[1], a2 = pb2[2], a3 = pb2[3];
            const v2f xp0 = (v2f){xa.x, xa.y}, xp1 = (v2f){xa.z, xa.w};
            const v2f xp2 = (v2f){xc.x, xc.y}, xp3 = (v2f){xc.z, xc.w};
            a0 = __builtin_elementwise_fma(xp0, wi[0][0], a0);
            a1 = __builtin_elementwise_fma(xp0, wi[1][0], a1);
            a2 = __builtin_elementwise_fma(xp0, wi[2][0], a2);
            a3 = __builtin_elementwise_fma(xp0, wi[3][0], a3);
            a0 = __builtin_elementwise_fma(xp1, wi[0][1], a0);
            a1 = __builtin_elementwise_fma(xp1, wi[1][1], a1);
            a2 = __builtin_elementwise_fma(xp1, wi[2][1], a2);
            a3 = __builtin_elementwise_fma(xp1, wi[3][1], a3);
            a0 = __builtin_elementwise_fma(xp2, wi[0][2], a0);
            a1 = __builtin_elementwise_fma(xp2, wi[1][2], a1);
            a2 = __builtin_elementwise_fma(xp2, wi[2][2], a2);
            a3 = __builtin_elementwise_fma(xp2, wi[3][2], a3);
            a0 = __builtin_elementwise_fma(xp3, wi[0][3], a0);
            a1 = __builtin_elementwise_fma(xp3, wi[1][3], a1);
            a2 = __builtin_elementwise_fma(xp3, wi[2][3], a2);
            a3 = __builtin_elementwise_fma(xp3, wi[3][3], a3);

            const v2f hp0 = (v2f){h0.x, h0.y}, hp1 = (v2f){h0.z, h0.w};
            const v2f hp2 = (v2f){h1.x, h1.y}, hp3 = (v2f){h1.z, h1.w};
            const v2f hp4 = (v2f){h2.x, h2.y}, hp5 = (v2f){h2.z, h2.w};
            const v2f hp6 = (v2f){h3.x, h3.y}, hp7 = (v2f){h3.z, h3.w};
            a0 = __builtin_elementwise_fma(hp0, wh[0][0], a0);
            a1 = __builtin_elementwise_fma(hp0, wh[1][0], a1);
            a2 = __builtin_elementwise_fma(hp0, wh[2][0], a2);
            a3 = __builtin_elementwise_fma(hp0, wh[3][0], a3);
            a0 = __builtin_elementwise_fma(hp1, wh[0][1], a0);
            a1 = __builtin_elementwise_fma(hp1, wh[1][1], a1);
            a2 = __builtin_elementwise_fma(hp1, wh[2][1], a2);
            a3 = __builtin_elementwise_fma(hp1, wh[3][1], a3);
            a0 = __builtin_elementwise_fma(hp2, wh[0][2], a0);
            a1 = __builtin_elementwise_fma(hp2, wh[1][2], a1);
            a2 = __builtin_elementwise_fma(hp2, wh[2][2], a2);
            a3 = __builtin_elementwise_fma(hp2, wh[3][2], a3);
            a0 = __builtin_elementwise_fma(hp3, wh[0][3], a0);
            a1 = __builtin_elementwise_fma(hp3, wh[1][3], a1);
            a2 = __builtin_elementwise_fma(hp3, wh[2][3], a2);
            a3 = __builtin_elementwise_fma(hp3, wh[3][3], a3);
            a0 = __builtin_elementwise_fma(hp4, wh[0][4], a0);
            a1 = __builtin_elementwise_fma(hp4, wh[1][4], a1);
            a2 = __builtin_elementwise_fma(hp4, wh[2][4], a2);
            a3 = __builtin_elementwise_fma(hp4, wh[3][4], a3);
            a0 = __builtin_elementwise_fma(hp5, wh[0][5], a0);
            a1 = __builtin_elementwise_fma(hp5, wh[1][5], a1);
            a2 = __builtin_elementwise_fma(hp5, wh[2][5], a2);
            a3 = __builtin_elementwise_fma(hp5, wh[3][5], a3);
            a0 = __builtin_elementwise_fma(hp6, wh[0][6], a0);
            a1 = __builtin_elementwise_fma(hp6, wh[1][6], a1);
            a2 = __builtin_elementwise_fma(hp6, wh[2][6], a2);
            a3 = __builtin_elementwise_fma(hp6, wh[3][6], a3);
            a0 = __builtin_elementwise_fma(hp7, wh[0][7], a0);
            a1 = __builtin_elementwise_fma(hp7, wh[1][7], a1);
            a2 = __builtin_elementwise_fma(hp7, wh[2][7], a2);
            a3 = __builtin_elementwise_fma(hp7, wh[3][7], a3);

            float g0 = a0.x + a0.y;
            float g1 = a1.x + a1.y;
            float g2 = a2.x + a2.y;
            float g3 = a3.x + a3.y;
            g0 += __shfl_xor(g0, 32);   // full i gate
            g1 += __shfl_xor(g1, 32);   // f
            g2 += __shfl_xor(g2, 32);   // g
            g3 += __shfl_xor(g3, 32);   // o

            const float si = sigm(g0);
            const float sf = sigm(g1);
            const float tg = tanh_fast(g2);
            const float so = sigm(g3);
            c = fmaf(sf, c, si * tg);
            h = so * tanh_fast(c);

            // stage next x chunk into the other buffer (covered by barrier below)
            if (tt == CH - 1 && more) {
                *(float4*)(xsb + ((ci + 1) & 1) * (CH * FF) + sl * FF + wl * 4) = nf;
            }
            if (hi == 0) hsb[((tt & 1) ^ 1) * HH + kk] = h;
            __syncthreads();
        }
    }

    // hidden[b][0:32] = h_fwd, hidden[b][32:64] = h_bwd
    if (hi == 0) hidden[(size_t)bb * 64 + dir * HH + kk] = h;
}

// FC1 + per-block partial of FC2. Grid: 32 blocks x 256 threads.
__global__ __launch_bounds__(256)
void fc_partial_kernel(const float* __restrict__ hidden,
                       const float* __restrict__ Wfh, const float* __restrict__ bfh,
                       const float* __restrict__ Wfo,
                       float* __restrict__ partials)
{
    __shared__ float wsh[OO * 64];
    const int tid = threadIdx.x;
    for (int i = tid; i < OO * 64; i += 256) wsh[i] = Wfh[i];
    __syncthreads();

    const int r   = tid >> 3;
    const int o   = tid & 7;
    const int row = blockIdx.x * 32 + r;

    const float* hrow = hidden + (size_t)row * 64;
    float acc = bfh[o];
#pragma unroll
    for (int j = 0; j < 64; ++j) acc += hrow[j] * wsh[o * 64 + j];

    const int fidx = blockIdx.x * 256 + tid;

    float pv[OO];
#pragma unroll
    for (int o2 = 0; o2 < OO; ++o2) pv[o2] = Wfo[(size_t)o2 * (BB * OO) + fidx] * acc;

    __shared__ float red[4][OO];
#pragma unroll
    for (int o2 = 0; o2 < OO; ++o2) {
        float v = pv[o2];
        for (int off = 32; off > 0; off >>= 1) v += __shfl_down(v, off);
        if ((tid & 63) == 0) red[tid >> 6][o2] = v;
    }
    __syncthreads();
    if (tid < OO) {
        partials[blockIdx.x * OO + tid] =
            red[0][tid] + red[1][tid] + red[2][tid] + red[3][tid];
    }
}

__global__ void finalize_kernel(const float* __restrict__ partials,
                                const float* __restrict__ bfo,
                                float* __restrict__ out)
{
    __shared__ float s[OO];
    const int tid = threadIdx.x;
    if (tid < OO) {
        float acc = bfo[tid];
        for (int b = 0; b < 32; ++b) acc += partials[b * OO + tid];
        s[tid] = acc;
    }
    __syncthreads();
    if (tid == 0) {
        float m = s[0];
        for (int i = 1; i < OO; ++i) m = fmaxf(m, s[i]);
        float e[OO], sum = 0.0f;
        for (int i = 0; i < OO; ++i) { e[i] = expf(s[i] - m); sum += e[i]; }
        for (int i = 0; i < OO; ++i) out[i] = e[i] / sum;
    }
}

extern "C" void kernel_launch(void* const* d_in, const int* in_sizes, int n_in,
                              void* d_out, int out_size, void* d_ws, size_t ws_size,
                              hipStream_t stream) {
    const float* x     = (const float*)d_in[0];
    const float* Wih_f = (const float*)d_in[1];
    const float* Whh_f = (const float*)d_in[2];
    const float* b_f   = (const float*)d_in[3];
    const float* Wih_b = (const float*)d_in[4];
    const float* Whh_b = (const float*)d_in[5];
    const float* b_b   = (const float*)d_in[6];
    const float* Wfh   = (const float*)d_in[7];
    const float* bfh   = (const float*)d_in[8];
    const float* Wfo   = (const float*)d_in[9];
    const float* bfo   = (const float*)d_in[10];

    float* hidden   = (float*)d_ws;
    float* partials = hidden + (size_t)BB * 64;

    lstm_seq_kernel<<<2 * BB, 64, 0, stream>>>(x, Wih_f, Whh_f, b_f,
                                               Wih_b, Whh_b, b_b, hidden);
    fc_partial_kernel<<<32, 256, 0, stream>>>(hidden, Wfh, bfh, Wfo, partials);
    finalize_kernel<<<1, 64, 0, stream>>>(partials, bfo, (float*)d_out);
}

// Round 4
// 217.931 us; speedup vs baseline: 1.3690x; 1.0503x over previous
//
#include <hip/hip_runtime.h>

#define TT 512
#define BB 1024
#define FF 16
#define HH 32
#define OO 8
#define CH 16   // timesteps per x-chunk staged through LDS

typedef float v2f __attribute__((ext_vector_type(2)));

__device__ __forceinline__ float rcp_fast(float x) { return __builtin_amdgcn_rcpf(x); }
// inputs to these are PRE-SCALED by log2e (resp. 2*log2e), so plain exp2.
__device__ __forceinline__ float sigm2(float y) {
    return rcp_fast(1.0f + __builtin_amdgcn_exp2f(-y));
}

// real pin: "+v" marks the value as redefined by the asm, so the compiler
// cannot re-materialize it from memory inside the loop.
#define PIN(a) asm volatile("" : "+v"(a))

// One wave per block, one sequence per wave (2048 blocks, 2 waves/SIMD).
// k-split layout: lane (hi,kk) computes ALL 4 gate rows {kk,+32,+64,+96}
// over k-half hi. 96 weight floats/lane as 48 v2f pinned in VGPRs.
// Gate recombine: 4x shfl_xor(32). x staged through LDS in 16-step chunks
// (one dwordx4/lane covers a chunk, issued 16 steps early). h double-buffered
// in LDS, single barrier per step (1-wave block => barrier is just waitcnt).
__global__ __launch_bounds__(64, 2)
void lstm_seq_kernel(const float* __restrict__ x,
                     const float* __restrict__ Wih_f, const float* __restrict__ Whh_f,
                     const float* __restrict__ b_f,
                     const float* __restrict__ Wih_b, const float* __restrict__ Whh_b,
                     const float* __restrict__ b_b,
                     float* __restrict__ hidden)
{
    const int bid  = blockIdx.x;          // 0..2047
    const int dir  = bid >> 10;           // 0 = fwd, 1 = bwd
    const int bb   = bid & (BB - 1);      // batch row
    const int lane = threadIdx.x;
    const int hi   = lane >> 5;           // k-half
    const int kk   = lane & 31;           // hidden index (row)

    const float* __restrict__ Wih  = dir ? Wih_b : Wih_f;
    const float* __restrict__ Whh  = dir ? Whh_b : Whh_f;
    const float* __restrict__ bias = dir ? b_b   : b_f;

    // gate scale: i,f,o sigmoid -> log2e; g tanh(y)=2*sigm2(2*log2e*y)-1 -> 2*log2e
    const float LOG2E = 1.4426950408889634f;

    // ---- stage this lane's weight slices: 4 gates x (8 x-k + 16 h-k) ----
    v2f wi[4][4];   // x-part:  4 v2f per gate
    v2f wh[4][8];   // h-part:  8 v2f per gate
    v2f pb2[4];     // bias (hi==0 only) packed as {b*scale, 0}
#pragma unroll
    for (int g = 0; g < 4; ++g) {
        const float sc = (g == 2) ? 2.0f * LOG2E : LOG2E;
        const int row = kk + g * HH;
        const float4* pi = (const float4*)(Wih + row * FF + hi * 8);
        float4 a = pi[0], b = pi[1];
        wi[g][0] = (v2f){a.x * sc, a.y * sc}; wi[g][1] = (v2f){a.z * sc, a.w * sc};
        wi[g][2] = (v2f){b.x * sc, b.y * sc}; wi[g][3] = (v2f){b.z * sc, b.w * sc};
        const float4* ph = (const float4*)(Whh + row * HH + hi * 16);
        float4 c0 = ph[0], c1 = ph[1], c2 = ph[2], c3 = ph[3];
        wh[g][0] = (v2f){c0.x * sc, c0.y * sc}; wh[g][1] = (v2f){c0.z * sc, c0.w * sc};
        wh[g][2] = (v2f){c1.x * sc, c1.y * sc}; wh[g][3] = (v2f){c1.z * sc, c1.w * sc};
        wh[g][4] = (v2f){c2.x * sc, c2.y * sc}; wh[g][5] = (v2f){c2.z * sc, c2.w * sc};
        wh[g][6] = (v2f){c3.x * sc, c3.y * sc}; wh[g][7] = (v2f){c3.z * sc, c3.w * sc};
        pb2[g] = (v2f){hi ? 0.0f : bias[row] * sc, 0.0f};
    }
#pragma unroll
    for (int g = 0; g < 4; ++g) {
        PIN(wi[g][0]); PIN(wi[g][1]); PIN(wi[g][2]); PIN(wi[g][3]);
        PIN(wh[g][0]); PIN(wh[g][1]); PIN(wh[g][2]); PIN(wh[g][3]);
        PIN(wh[g][4]); PIN(wh[g][5]); PIN(wh[g][6]); PIN(wh[g][7]);
        PIN(pb2[g]);
    }

    __shared__ __align__(16) float xsb[2 * CH * FF];  // 2 KB: two x chunks
    __shared__ __align__(16) float hsb[2 * HH];       // double-buffered h

    // ---- x chunk staging: lane (sl,wl) covers step sl, quarter wl ----
    const int sl = lane >> 2;             // 0..15: step within chunk
    const int wl = lane & 3;              // 0..3 : float4 quarter
    const int t0 = dir ? (TT - 1 - sl) : sl;
    const float* xp = x + (size_t)t0 * (BB * FF) + (size_t)bb * FF + wl * 4;
    const ptrdiff_t dstep = (dir ? -(ptrdiff_t)CH : (ptrdiff_t)CH) * (BB * FF);

    {
        float4 f0 = *(const float4*)xp;
        *(float4*)(xsb + sl * FF + wl * 4) = f0;
    }
    xp += dstep;
    if (hi == 0) hsb[kk] = 0.0f;
    __syncthreads();

    float c = 0.0f, h = 0.0f;

    for (int ci = 0; ci < TT / CH; ++ci) {
        const bool more = (ci + 1 < TT / CH);
        float4 nf;
        if (more) { nf = *(const float4*)xp; xp += dstep; }   // chunk ci+1, 16 steps early

        const int xbase = (ci & 1) * (CH * FF) + hi * 8;
#pragma unroll
        for (int tt = 0; tt < CH; ++tt) {
            // x slice: 4 v2f (broadcast within half-wave)
            const v2f* xv = (const v2f*)(xsb + xbase + tt * FF);
            const v2f xp0 = xv[0], xp1 = xv[1], xp2 = xv[2], xp3 = xv[3];
            // h slice: 8 v2f
            const v2f* hv = (const v2f*)(hsb + (tt & 1) * HH + hi * 16);
            const v2f hp0 = hv[0], hp1 = hv[1], hp2 = hv[2], hp3 = hv[3];
            const v2f hp4 = hv[4], hp5 = hv[5], hp6 = hv[6], hp7 = hv[7];

            v2f a0 = __builtin_elementwise_fma(xp0, wi[0][0], pb2[0]);
            v2f a1 = __builtin_elementwise_fma(xp0, wi[1][0], pb2[1]);
            v2f a2 = __builtin_elementwise_fma(xp0, wi[2][0], pb2[2]);
            v2f a3 = __builtin_elementwise_fma(xp0, wi[3][0], pb2[3]);
            a0 = __builtin_elementwise_fma(xp1, wi[0][1], a0);
            a1 = __builtin_elementwise_fma(xp1, wi[1][1], a1);
            a2 = __builtin_elementwise_fma(xp1, wi[2][1], a2);
            a3 = __builtin_elementwise_fma(xp1, wi[3][1], a3);
            a0 = __builtin_elementwise_fma(xp2, wi[0][2], a0);
            a1 = __builtin_elementwise_fma(xp2, wi[1][2], a1);
            a2 = __builtin_elementwise_fma(xp2, wi[2][2], a2);
            a3 = __builtin_elementwise_fma(xp2, wi[3][2], a3);
            a0 = __builtin_elementwise_fma(xp3, wi[0][3], a0);
            a1 = __builtin_elementwise_fma(xp3, wi[1][3], a1);
            a2 = __builtin_elementwise_fma(xp3, wi[2][3], a2);
            a3 = __builtin_elementwise_fma(xp3, wi[3][3], a3);

            a0 = __builtin_elementwise_fma(hp0, wh[0][0], a0);
            a1 = __builtin_elementwise_fma(hp0, wh[1][0], a1);
            a2 = __builtin_elementwise_fma(hp0, wh[2][0], a2);
            a3 = __builtin_elementwise_fma(hp0, wh[3][0], a3);
            a0 = __builtin_elementwise_fma(hp1, wh[0][1], a0);
            a1 = __builtin_elementwise_fma(hp1, wh[1][1], a1);
            a2 = __builtin_elementwise_fma(hp1, wh[2][1], a2);
            a3 = __builtin_elementwise_fma(hp1, wh[3][1], a3);
            a0 = __builtin_elementwise_fma(hp2, wh[0][2], a0);
            a1 = __builtin_elementwise_fma(hp2, wh[1][2], a1);
            a2 = __builtin_elementwise_fma(hp2, wh[2][2], a2);
            a3 = __builtin_elementwise_fma(hp2, wh[3][2], a3);
            a0 = __builtin_elementwise_fma(hp3, wh[0][3], a0);
            a1 = __builtin_elementwise_fma(hp3, wh[1][3], a1);
            a2 = __builtin_elementwise_fma(hp3, wh[2][3], a2);
            a3 = __builtin_elementwise_fma(hp3, wh[3][3], a3);
            a0 = __builtin_elementwise_fma(hp4, wh[0][4], a0);
            a1 = __builtin_elementwise_fma(hp4, wh[1][4], a1);
            a2 = __builtin_elementwise_fma(hp4, wh[2][4], a2);
            a3 = __builtin_elementwise_fma(hp4, wh[3][4], a3);
            a0 = __builtin_elementwise_fma(hp5, wh[0][5], a0);
            a1 = __builtin_elementwise_fma(hp5, wh[1][5], a1);
            a2 = __builtin_elementwise_fma(hp5, wh[2][5], a2);
            a3 = __builtin_elementwise_fma(hp5, wh[3][5], a3);
            a0 = __builtin_elementwise_fma(hp6, wh[0][6], a0);
            a1 = __builtin_elementwise_fma(hp6, wh[1][6], a1);
            a2 = __builtin_elementwise_fma(hp6, wh[2][6], a2);
            a3 = __builtin_elementwise_fma(hp6, wh[3][6], a3);
            a0 = __builtin_elementwise_fma(hp7, wh[0][7], a0);
            a1 = __builtin_elementwise_fma(hp7, wh[1][7], a1);
            a2 = __builtin_elementwise_fma(hp7, wh[2][7], a2);
            a3 = __builtin_elementwise_fma(hp7, wh[3][7], a3);

            float g0 = a0.x + a0.y;     // pre-scaled by log2e
            float g1 = a1.x + a1.y;
            float g2 = a2.x + a2.y;     // pre-scaled by 2*log2e
            float g3 = a3.x + a3.y;
            g0 += __shfl_xor(g0, 32);   // i
            g1 += __shfl_xor(g1, 32);   // f
            g2 += __shfl_xor(g2, 32);   // g
            g3 += __shfl_xor(g3, 32);   // o

            const float si = sigm2(g0);
            const float sf = sigm2(g1);
            const float tg = fmaf(2.0f, sigm2(g2), -1.0f);   // tanh(g)
            const float so = sigm2(g3);
            c = fmaf(sf, c, si * tg);
            const float th = fmaf(2.0f, sigm2(2.0f * LOG2E * c), -1.0f);  // tanh(c)
            h = so * th;

            if (tt == CH - 1 && more) {
                *(float4*)(xsb + ((ci + 1) & 1) * (CH * FF) + sl * FF + wl * 4) = nf;
            }
            if (hi == 0) hsb[((tt & 1) ^ 1) * HH + kk] = h;
            __syncthreads();
        }
    }

    if (hi == 0) hidden[(size_t)bb * 64 + dir * HH + kk] = h;
}

// FC1 + per-block partial of FC2. Grid: 32 blocks x 256 threads.
__global__ __launch_bounds__(256)
void fc_partial_kernel(const float* __restrict__ hidden,
                       const float* __restrict__ Wfh, const float* __restrict__ bfh,
                       const float* __restrict__ Wfo,
                       float* __restrict__ partials)
{
    __shared__ float wsh[OO * 64];
    const int tid = threadIdx.x;
    for (int i = tid; i < OO * 64; i += 256) wsh[i] = Wfh[i];
    __syncthreads();

    const int r   = tid >> 3;
    const int o   = tid & 7;
    const int row = blockIdx.x * 32 + r;

    const float* hrow = hidden + (size_t)row * 64;
    float acc = bfh[o];
#pragma unroll
    for (int j = 0; j < 64; ++j) acc += hrow[j] * wsh[o * 64 + j];

    const int fidx = blockIdx.x * 256 + tid;

    float pv[OO];
#pragma unroll
    for (int o2 = 0; o2 < OO; ++o2) pv[o2] = Wfo[(size_t)o2 * (BB * OO) + fidx] * acc;

    __shared__ float red[4][OO];
#pragma unroll
    for (int o2 = 0; o2 < OO; ++o2) {
        float v = pv[o2];
        for (int off = 32; off > 0; off >>= 1) v += __shfl_down(v, off);
        if ((tid & 63) == 0) red[tid >> 6][o2] = v;
    }
    __syncthreads();
    if (tid < OO) {
        partials[blockIdx.x * OO + tid] =
            red[0][tid] + red[1][tid] + red[2][tid] + red[3][tid];
    }
}

__global__ void finalize_kernel(const float* __restrict__ partials,
                                const float* __restrict__ bfo,
                                float* __restrict__ out)
{
    __shared__ float s[OO];
    const int tid = threadIdx.x;
    if (tid < OO) {
        float acc = bfo[tid];
        for (int b = 0; b < 32; ++b) acc += partials[b * OO + tid];
        s[tid] = acc;
    }
    __syncthreads();
    if (tid == 0) {
        float m = s[0];
        for (int i = 1; i < OO; ++i) m = fmaxf(m, s[i]);
        float e[OO], sum = 0.0f;
        for (int i = 0; i < OO; ++i) { e[i] = expf(s[i] - m); sum += e[i]; }
        for (int i = 0; i < OO; ++i) out[i] = e[i] / sum;
    }
}

extern "C" void kernel_launch(void* const* d_in, const int* in_sizes, int n_in,
                              void* d_out, int out_size, void* d_ws, size_t ws_size,
                              hipStream_t stream) {
    const float* x     = (const float*)d_in[0];
    const float* Wih_f = (const float*)d_in[1];
    const float* Whh_f = (const float*)d_in[2];
    const float* b_f   = (const float*)d_in[3];
    const float* Wih_b = (const float*)d_in[4];
    const float* Whh_b = (const float*)d_in[5];
    const float* b_b   = (const float*)d_in[6];
    const float* Wfh   = (const float*)d_in[7];
    const float* bfh   = (const float*)d_in[8];
    const float* Wfo   = (const float*)d_in[9];
    const float* bfo   = (const float*)d_in[10];

    float* hidden   = (float*)d_ws;
    float* partials = hidden + (size_t)BB * 64;

    lstm_seq_kernel<<<2 * BB, 64, 0, stream>>>(x, Wih_f, Whh_f, b_f,
                                               Wih_b, Whh_b, b_b, hidden);
    fc_partial_kernel<<<32, 256, 0, stream>>>(hidden, Wfh, bfh, Wfo, partials);
    finalize_kernel<<<1, 64, 0, stream>>>(partials, bfo, (float*)d_out);
}

// Round 5
// 216.759 us; speedup vs baseline: 1.3764x; 1.0054x over previous
//
#include <hip/hip_runtime.h>

#define TT 512
#define BB 1024
#define FF 16
#define HH 32
#define OO 8
#define CH 16   // timesteps per x-chunk staged through LDS

typedef float v2f __attribute__((ext_vector_type(2)));

__device__ __forceinline__ float rcp_fast(float x) { return __builtin_amdgcn_rcpf(x); }
// inputs are PRE-SCALED by log2e (resp. 2*log2e), so plain exp2.
__device__ __forceinline__ float sigm2(float y) {
    return rcp_fast(1.0f + __builtin_amdgcn_exp2f(-y));
}

// In-loop pin: executed EVERY timestep, so the values must sit in arch VGPRs
// across the whole loop — no AGPR shuttling, no rematerialization.
#define PIN13(a,b,c,d,e,f,g,h,i,j,k,l,m) \
    asm volatile("" : "+v"(a),"+v"(b),"+v"(c),"+v"(d),"+v"(e),"+v"(f),"+v"(g), \
                      "+v"(h),"+v"(i),"+v"(j),"+v"(k),"+v"(l),"+v"(m))

// One wave per block, one sequence per wave (2048 blocks, 2 waves/SIMD).
// k-split: lane (hi,kk) computes ALL 4 gate rows {kk,+32,+64,+96} over k-half
// hi. 96 weight floats/lane as 48 v2f pinned in VGPRs (in-loop asm).
// Gate recombine: 4x shfl_xor(32). x staged through LDS in 16-step chunks.
// h double-buffered in LDS, one barrier per step (1-wave block => waitcnt).
__global__ __launch_bounds__(64, 2)
void lstm_seq_kernel(const float* __restrict__ x,
                     const float* __restrict__ Wih_f, const float* __restrict__ Whh_f,
                     const float* __restrict__ b_f,
                     const float* __restrict__ Wih_b, const float* __restrict__ Whh_b,
                     const float* __restrict__ b_b,
                     float* __restrict__ hidden)
{
    const int bid  = blockIdx.x;          // 0..2047
    const int dir  = bid >> 10;           // 0 = fwd, 1 = bwd
    const int bb   = bid & (BB - 1);      // batch row
    const int lane = threadIdx.x;
    const int hi   = lane >> 5;           // k-half
    const int kk   = lane & 31;           // hidden index (row)

    const float* __restrict__ Wih  = dir ? Wih_b : Wih_f;
    const float* __restrict__ Whh  = dir ? Whh_b : Whh_f;
    const float* __restrict__ bias = dir ? b_b   : b_f;

    const float LOG2E  = 1.4426950408889634f;
    const float L2E2   = 2.0f * LOG2E;

    // ---- stage this lane's weight slices: 4 gates x (8 x-k + 16 h-k) ----
    v2f wi[4][4];   // x-part
    v2f wh[4][8];   // h-part
    v2f pb2[4];     // bias (hi==0 only) packed {b*scale, 0}
#pragma unroll
    for (int g = 0; g < 4; ++g) {
        const float sc = (g == 2) ? L2E2 : LOG2E;
        const int row = kk + g * HH;
        const float4* pi = (const float4*)(Wih + row * FF + hi * 8);
        float4 a = pi[0], b = pi[1];
        wi[g][0] = (v2f){a.x * sc, a.y * sc}; wi[g][1] = (v2f){a.z * sc, a.w * sc};
        wi[g][2] = (v2f){b.x * sc, b.y * sc}; wi[g][3] = (v2f){b.z * sc, b.w * sc};
        const float4* ph = (const float4*)(Whh + row * HH + hi * 16);
        float4 c0 = ph[0], c1 = ph[1], c2 = ph[2], c3 = ph[3];
        wh[g][0] = (v2f){c0.x * sc, c0.y * sc}; wh[g][1] = (v2f){c0.z * sc, c0.w * sc};
        wh[g][2] = (v2f){c1.x * sc, c1.y * sc}; wh[g][3] = (v2f){c1.z * sc, c1.w * sc};
        wh[g][4] = (v2f){c2.x * sc, c2.y * sc}; wh[g][5] = (v2f){c2.z * sc, c2.w * sc};
        wh[g][6] = (v2f){c3.x * sc, c3.y * sc}; wh[g][7] = (v2f){c3.z * sc, c3.w * sc};
        pb2[g] = (v2f){hi ? 0.0f : bias[row] * sc, 0.0f};
    }

    __shared__ __align__(16) float xsb[2 * CH * FF];  // two x chunks
    __shared__ __align__(16) float hsb[2 * HH];       // double-buffered h

    // ---- x chunk staging: lane (sl,wl) covers step sl, quarter wl ----
    const int sl = lane >> 2;
    const int wl = lane & 3;
    const int t0 = dir ? (TT - 1 - sl) : sl;
    const float* xp = x + (size_t)t0 * (BB * FF) + (size_t)bb * FF + wl * 4;
    const ptrdiff_t dstep = (dir ? -(ptrdiff_t)CH : (ptrdiff_t)CH) * (BB * FF);

    {
        float4 f0 = *(const float4*)xp;
        *(float4*)(xsb + sl * FF + wl * 4) = f0;
    }
    xp += dstep;
    if (hi == 0) hsb[kk] = 0.0f;
    __syncthreads();

    float c = 0.0f, h = 0.0f;

    for (int ci = 0; ci < TT / CH; ++ci) {
        const bool more = (ci + 1 < TT / CH);
        float4 nf;
        if (more) { nf = *(const float4*)xp; xp += dstep; }   // 16 steps early

        const int xbase = (ci & 1) * (CH * FF) + hi * 8;
#pragma unroll
        for (int tt = 0; tt < CH; ++tt) {
            // force arch-VGPR residency of all weights EVERY iteration
            PIN13(wi[0][0], wi[0][1], wi[0][2], wi[0][3],
                  wi[1][0], wi[1][1], wi[1][2], wi[1][3],
                  wi[2][0], wi[2][1], wi[2][2], wi[2][3], pb2[0]);
            PIN13(wi[3][0], wi[3][1], wi[3][2], wi[3][3],
                  wh[0][0], wh[0][1], wh[0][2], wh[0][3],
                  wh[0][4], wh[0][5], wh[0][6], wh[0][7], pb2[1]);
            PIN13(wh[1][0], wh[1][1], wh[1][2], wh[1][3],
                  wh[1][4], wh[1][5], wh[1][6], wh[1][7],
                  wh[2][0], wh[2][1], wh[2][2], wh[2][3], pb2[2]);
            PIN13(wh[2][4], wh[2][5], wh[2][6], wh[2][7],
                  wh[3][0], wh[3][1], wh[3][2], wh[3][3],
                  wh[3][4], wh[3][5], wh[3][6], wh[3][7], pb2[3]);

            const v2f* xv = (const v2f*)(xsb + xbase + tt * FF);
            const v2f xp0 = xv[0], xp1 = xv[1], xp2 = xv[2], xp3 = xv[3];
            const v2f* hv = (const v2f*)(hsb + (tt & 1) * HH + hi * 16);
            const v2f hp0 = hv[0], hp1 = hv[1], hp2 = hv[2], hp3 = hv[3];
            const v2f hp4 = hv[4], hp5 = hv[5], hp6 = hv[6], hp7 = hv[7];

            v2f a0 = __builtin_elementwise_fma(xp0, wi[0][0], pb2[0]);
            v2f a1 = __builtin_elementwise_fma(xp0, wi[1][0], pb2[1]);
            v2f a2 = __builtin_elementwise_fma(xp0, wi[2][0], pb2[2]);
            v2f a3 = __builtin_elementwise_fma(xp0, wi[3][0], pb2[3]);
            a0 = __builtin_elementwise_fma(xp1, wi[0][1], a0);
            a1 = __builtin_elementwise_fma(xp1, wi[1][1], a1);
            a2 = __builtin_elementwise_fma(xp1, wi[2][1], a2);
            a3 = __builtin_elementwise_fma(xp1, wi[3][1], a3);
            a0 = __builtin_elementwise_fma(xp2, wi[0][2], a0);
            a1 = __builtin_elementwise_fma(xp2, wi[1][2], a1);
            a2 = __builtin_elementwise_fma(xp2, wi[2][2], a2);
            a3 = __builtin_elementwise_fma(xp2, wi[3][2], a3);
            a0 = __builtin_elementwise_fma(xp3, wi[0][3], a0);
            a1 = __builtin_elementwise_fma(xp3, wi[1][3], a1);
            a2 = __builtin_elementwise_fma(xp3, wi[2][3], a2);
            a3 = __builtin_elementwise_fma(xp3, wi[3][3], a3);

            a0 = __builtin_elementwise_fma(hp0, wh[0][0], a0);
            a1 = __builtin_elementwise_fma(hp0, wh[1][0], a1);
            a2 = __builtin_elementwise_fma(hp0, wh[2][0], a2);
            a3 = __builtin_elementwise_fma(hp0, wh[3][0], a3);
            a0 = __builtin_elementwise_fma(hp1, wh[0][1], a0);
            a1 = __builtin_elementwise_fma(hp1, wh[1][1], a1);
            a2 = __builtin_elementwise_fma(hp1, wh[2][1], a2);
            a3 = __builtin_elementwise_fma(hp1, wh[3][1], a3);
            a0 = __builtin_elementwise_fma(hp2, wh[0][2], a0);
            a1 = __builtin_elementwise_fma(hp2, wh[1][2], a1);
            a2 = __builtin_elementwise_fma(hp2, wh[2][2], a2);
            a3 = __builtin_elementwise_fma(hp2, wh[3][2], a3);
            a0 = __builtin_elementwise_fma(hp3, wh[0][3], a0);
            a1 = __builtin_elementwise_fma(hp3, wh[1][3], a1);
            a2 = __builtin_elementwise_fma(hp3, wh[2][3], a2);
            a3 = __builtin_elementwise_fma(hp3, wh[3][3], a3);
            a0 = __builtin_elementwise_fma(hp4, wh[0][4], a0);
            a1 = __builtin_elementwise_fma(hp4, wh[1][4], a1);
            a2 = __builtin_elementwise_fma(hp4, wh[2][4], a2);
            a3 = __builtin_elementwise_fma(hp4, wh[3][4], a3);
            a0 = __builtin_elementwise_fma(hp5, wh[0][5], a0);
            a1 = __builtin_elementwise_fma(hp5, wh[1][5], a1);
            a2 = __builtin_elementwise_fma(hp5, wh[2][5], a2);
            a3 = __builtin_elementwise_fma(hp5, wh[3][5], a3);
            a0 = __builtin_elementwise_fma(hp6, wh[0][6], a0);
            a1 = __builtin_elementwise_fma(hp6, wh[1][6], a1);
            a2 = __builtin_elementwise_fma(hp6, wh[2][6], a2);
            a3 = __builtin_elementwise_fma(hp6, wh[3][6], a3);
            a0 = __builtin_elementwise_fma(hp7, wh[0][7], a0);
            a1 = __builtin_elementwise_fma(hp7, wh[1][7], a1);
            a2 = __builtin_elementwise_fma(hp7, wh[2][7], a2);
            a3 = __builtin_elementwise_fma(hp7, wh[3][7], a3);

            float g0 = a0.x + a0.y;     // pre-scaled by log2e
            float g1 = a1.x + a1.y;
            float g2 = a2.x + a2.y;     // pre-scaled by 2*log2e
            float g3 = a3.x + a3.y;
            g0 += __shfl_xor(g0, 32);   // i
            g1 += __shfl_xor(g1, 32);   // f
            g2 += __shfl_xor(g2, 32);   // g
            g3 += __shfl_xor(g3, 32);   // o

            const float si = sigm2(g0);
            const float sf = sigm2(g1);
            const float tg = fmaf(2.0f, sigm2(g2), -1.0f);   // tanh(g)
            const float so = sigm2(g3);
            c = fmaf(sf, c, si * tg);
            const float th = fmaf(2.0f, sigm2(L2E2 * c), -1.0f);  // tanh(c)
            h = so * th;

            if (tt == CH - 1 && more) {
                *(float4*)(xsb + ((ci + 1) & 1) * (CH * FF) + sl * FF + wl * 4) = nf;
            }
            if (hi == 0) hsb[((tt & 1) ^ 1) * HH + kk] = h;
            __syncthreads();
        }
    }

    if (hi == 0) hidden[(size_t)bb * 64 + dir * HH + kk] = h;
}

// FC1 + per-block partial of FC2. Grid: 32 blocks x 256 threads.
__global__ __launch_bounds__(256)
void fc_partial_kernel(const float* __restrict__ hidden,
                       const float* __restrict__ Wfh, const float* __restrict__ bfh,
                       const float* __restrict__ Wfo,
                       float* __restrict__ partials)
{
    __shared__ float wsh[OO * 64];
    const int tid = threadIdx.x;
    for (int i = tid; i < OO * 64; i += 256) wsh[i] = Wfh[i];
    __syncthreads();

    const int r   = tid >> 3;
    const int o   = tid & 7;
    const int row = blockIdx.x * 32 + r;

    const float* hrow = hidden + (size_t)row * 64;
    float acc = bfh[o];
#pragma unroll
    for (int j = 0; j < 64; ++j) acc += hrow[j] * wsh[o * 64 + j];

    const int fidx = blockIdx.x * 256 + tid;

    float pv[OO];
#pragma unroll
    for (int o2 = 0; o2 < OO; ++o2) pv[o2] = Wfo[(size_t)o2 * (BB * OO) + fidx] * acc;

    __shared__ float red[4][OO];
#pragma unroll
    for (int o2 = 0; o2 < OO; ++o2) {
        float v = pv[o2];
        for (int off = 32; off > 0; off >>= 1) v += __shfl_down(v, off);
        if ((tid & 63) == 0) red[tid >> 6][o2] = v;
    }
    __syncthreads();
    if (tid < OO) {
        partials[blockIdx.x * OO + tid] =
            red[0][tid] + red[1][tid] + red[2][tid] + red[3][tid];
    }
}

__global__ void finalize_kernel(const float* __restrict__ partials,
                                const float* __restrict__ bfo,
                                float* __restrict__ out)
{
    __shared__ float s[OO];
    const int tid = threadIdx.x;
    if (tid < OO) {
        float acc = bfo[tid];
        for (int b = 0; b < 32; ++b) acc += partials[b * OO + tid];
        s[tid] = acc;
    }
    __syncthreads();
    if (tid == 0) {
        float m = s[0];
        for (int i = 1; i < OO; ++i) m = fmaxf(m, s[i]);
        float e[OO], sum = 0.0f;
        for (int i = 0; i < OO; ++i) { e[i] = expf(s[i] - m); sum += e[i]; }
        for (int i = 0; i < OO; ++i) out[i] = e[i] / sum;
    }
}

extern "C" void kernel_launch(void* const* d_in, const int* in_sizes, int n_in,
                              void* d_out, int out_size, void* d_ws, size_t ws_size,
                              hipStream_t stream) {
    const float* x     = (const float*)d_in[0];
    const float* Wih_f = (const float*)d_in[1];
    const float* Whh_f = (const float*)d_in[2];
    const float* b_f   = (const float*)d_in[3];
    const float* Wih_b = (const float*)d_in[4];
    const float* Whh_b = (const float*)d_in[5];
    const float* b_b   = (const float*)d_in[6];
    const float* Wfh   = (const float*)d_in[7];
    const float* bfh   = (const float*)d_in[8];
    const float* Wfo   = (const float*)d_in[9];
    const float* bfo   = (const float*)d_in[10];

    float* hidden   = (float*)d_ws;
    float* partials = hidden + (size_t)BB * 64;

    lstm_seq_kernel<<<2 * BB, 64, 0, stream>>>(x, Wih_f, Whh_f, b_f,
                                               Wih_b, Whh_b, b_b, hidden);
    fc_partial_kernel<<<32, 256, 0, stream>>>(hidden, Wfh, bfh, Wfo, partials);
    finalize_kernel<<<1, 64, 0, stream>>>(partials, bfo, (float*)d_out);
}